// Round 1
// 1047.527 us; speedup vs baseline: 1.1908x; 1.1908x over previous
//
#include <hip/hip_runtime.h>
#include <math.h>

// SymmetricKMeans MI355X — R13: decouple the groups (kill the global lockstep).
// R12 counters: VALUBusy 10%, HBM 0.15%, Occ 15% -> latency/serialization bound.
// ~51us/iter vs <=15us/iter of compute => the per-iteration GLOBAL convergence
// rendezvous (+64 doubled-up CUs at 320 blocks) dominates. Changes:
//  - geometry: 2 blocks x 512 thr per group (160 blocks <= 256 CUs, uniform;
//    phase B halves; intra-group barrier is 2-party).
//  - groups RUN AHEAD independently. Per iteration a group only (a) fires one
//    report atomicAdd on a per-iteration line, (b) reads a per-group versioned
//    decision word. T is resolved by an in-order watermark sweep (closers mark
//    closed/conv per t; watermark advance is CAS-serialized so the FIRST
//    all-conv t wins exactly = reference T).
//  - per-iteration state (cls + centroids) goes to a 64-deep global ring so a
//    group that overran T emits exactly state(T). Lead bounded (<48+eps) by a
//    water guard; ring slot distance always < 64.
//  - exit decision is versioned and published per group by its rep block, read
//    by BOTH blocks right after the group barrier -> both break at the same
//    iteration (no barrier deadlock).
//  - FPS: per-pick critical path cut: per-lane 16-chain -> depth-4 tree;
//    cross-lane reduce via 4x DPP row_ror (rows of 16) + 2 shfl_xor (all lanes
//    end with the winner; final broadcast removed). (max d, min idx) selection
//    is a total order -> any reduction order is bit-identical.
// All FP op orders from R12 preserved (phase A distances, phase B sums/divs/
// norms, f64 score tree), so trajectories and T match bitwise.

#define NGRP   80
#define NPTS   1024
#define NCTR   512
#define MAXIT  300
#define NBLK   160
#define NTHR   512
#define RING   64
#define LEAD   48
#define OUT_CENT  81920
#define OUT_SCORE 204800

__device__ float4   g_cent[NGRP * NCTR];            // FPS output -> kmeans init
__device__ int      g_rcls[RING][NGRP * NPTS];      // per-iteration cls ring
__device__ float4   g_rcent[RING][NGRP * NCTR];     // per-iteration centroid ring
__device__ unsigned g_lbar[NGRP * 32];              // per-group barrier line
__device__ unsigned g_itcnt[MAXIT * 32];            // per-t: cnt<<16 | conv_sum
__device__ unsigned g_closed[MAXIT * 32];           // per-t: bit0 closed, bit1 allconv
__device__ unsigned g_gdec[NGRP * 32];              // per-group: ver<<16 | (T or 0)
__device__ unsigned g_T[32];                        // 0 unset, else T (iters run)
__device__ unsigned g_water[32];                    // contiguous closed prefix

// ---------------- threefry2x32, exactly as JAX (partitionable path) ----------------
__device__ __forceinline__ void tf2x32(unsigned k0, unsigned k1,
                                       unsigned x0, unsigned x1,
                                       unsigned &o0, unsigned &o1) {
  unsigned ks2 = k0 ^ k1 ^ 0x1BD11BDAu;
#define RND(r) { x0 += x1; x1 = (x1 << (r)) | (x1 >> (32 - (r))); x1 ^= x0; }
  x0 += k0; x1 += k1;
  RND(13) RND(15) RND(26) RND(6)
  x0 += k1;  x1 += ks2 + 1u;
  RND(17) RND(29) RND(16) RND(24)
  x0 += ks2; x1 += k0 + 2u;
  RND(13) RND(15) RND(26) RND(6)
  x0 += k0;  x1 += k1 + 3u;
  RND(17) RND(29) RND(16) RND(24)
  x0 += k1;  x1 += ks2 + 4u;
  RND(13) RND(15) RND(26) RND(6)
  x0 += ks2; x1 += k0 + 5u;
#undef RND
  o0 = x0; o1 = x1;
}

// (max value, min index) selection — total order, any reduction order is exact.
__device__ __forceinline__ void fps_comb(float &bv, int &bi, float ov, int oi) {
  if (ov > bv || (ov == bv && oi < bi)) { bv = ov; bi = oi; }
}

#define DPP_STEP(CTRL) {                                                   \
    float ov_ = __int_as_float(__builtin_amdgcn_update_dpp(                \
        0, __float_as_int(bv), (CTRL), 0xF, 0xF, true));                   \
    int oi_ = __builtin_amdgcn_update_dpp(0, bi, (CTRL), 0xF, 0xF, true);  \
    fps_comb(bv, bi, ov_, oi_); }

// ---------------- FPS: one WAVE per group, 16 points/lane ----------------
__global__ __launch_bounds__(64) void fps_kernel(const float *__restrict__ pos) {
  const int g = blockIdx.x, t = threadIdx.x;
  const int e = g & 7;
  __shared__ float sx[NPTS], sy[NPTS], sz[NPTS];
  if (g == 0) {  // re-init kmeans sync state every launch (graph-safe)
    for (int k = t; k < NGRP * 32; k += 64) { g_lbar[k] = 0u; g_gdec[k] = 0u; }
    for (int k = t; k < MAXIT * 32; k += 64) { g_itcnt[k] = 0u; g_closed[k] = 0u; }
    if (t == 0) { g_T[0] = 0u; g_water[0] = 0u; }
  }
  unsigned s0, s1, o0, o1;            // partitionable split + random_bits
  tf2x32(0u, 1u, 0u, 1u, s0, s1);
  tf2x32(s0, s1, 0u, (unsigned)g, o0, o1);
  int last = (int)((o0 ^ o1) & 1023u);

  const float *p = pos + (size_t)e * NPTS * 3;
  float x[16], y[16], z[16], md[16];
#pragma unroll
  for (int k = 0; k < 16; ++k) {
    int n = k * 64 + t;
    x[k] = p[n * 3 + 0]; y[k] = p[n * 3 + 1]; z[k] = p[n * 3 + 2];
    sx[n] = x[k]; sy[n] = y[k]; sz[n] = z[k];
    md[k] = __int_as_float(0x7f800000);
  }
  __syncthreads();
  for (int j = 0; j < NCTR; ++j) {
    const float lx = sx[last], ly = sy[last], lz = sz[last];
    if (t == 0) {   // centroid j = p[last]; c2 plain chain (unchanged)
      float c2 = __fadd_rn(__fadd_rn(__fmul_rn(lx, lx), __fmul_rn(ly, ly)),
                           __fmul_rn(lz, lz));
      g_cent[(size_t)g * NCTR + j] = make_float4(lx, ly, lz, c2);
    }
    float v[16]; int id[16];
#pragma unroll
    for (int k = 0; k < 16; ++k) {
      const float dx = __fsub_rn(x[k], lx), dy = __fsub_rn(y[k], ly),
                  dz = __fsub_rn(z[k], lz);
      const float d = __fadd_rn(__fadd_rn(__fmul_rn(dx, dx), __fmul_rn(dy, dy)),
                                __fmul_rn(dz, dz));
      md[k] = fminf(md[k], d);
      v[k] = md[k]; id[k] = k * 64 + t;
    }
#pragma unroll
    for (int s = 8; s >= 1; s >>= 1)
#pragma unroll
      for (int i = 0; i < s; ++i) fps_comb(v[i], id[i], v[i + s], id[i + s]);
    float bv = v[0]; int bi = id[0];
    // rows of 16 via DPP row_ror (circular windows 1,2,4,8 cover the row) ...
    DPP_STEP(0x121) DPP_STEP(0x122) DPP_STEP(0x124) DPP_STEP(0x128)
    // ... then across the 4 rows; every lane ends with the global winner.
    { float ov = __shfl_xor(bv, 16, 64); int oi = __shfl_xor(bi, 16, 64);
      fps_comb(bv, bi, ov, oi); }
    { float ov = __shfl_xor(bv, 32, 64); int oi = __shfl_xor(bi, 32, 64);
      fps_comb(bv, bi, ov, oi); }
    last = bi;                        // uniform across lanes (unique winner)
  }
}

// ---------------- per-group 2-block barrier (private cacheline) ----------------
__device__ __forceinline__ void lbar2(int grp) {
  __threadfence();
  __syncthreads();
  if (threadIdx.x == 0) {
    unsigned *cp = &g_lbar[grp * 32], *gp = &g_lbar[grp * 32 + 1];
    unsigned gen = __hip_atomic_load(gp, __ATOMIC_RELAXED, __HIP_MEMORY_SCOPE_AGENT);
    unsigned c = __hip_atomic_fetch_add(cp, 1u, __ATOMIC_ACQ_REL, __HIP_MEMORY_SCOPE_AGENT);
    if (c == 1u) {
      __hip_atomic_store(cp, 0u, __ATOMIC_RELAXED, __HIP_MEMORY_SCOPE_AGENT);
      __hip_atomic_fetch_add(gp, 1u, __ATOMIC_ACQ_REL, __HIP_MEMORY_SCOPE_AGENT);
    } else {
      long long guard = 0;
      while (__hip_atomic_load(gp, __ATOMIC_ACQUIRE, __HIP_MEMORY_SCOPE_AGENT) == gen) {
        __builtin_amdgcn_s_sleep(1);
        if (++guard > (1ll << 24)) break;  // safety valve
      }
    }
  }
  __syncthreads();
  __threadfence();
}

// ---------------- persistent decoupled k-means ----------------
__global__ __launch_bounds__(NTHR) void kmeans_kernel(
    const float *__restrict__ pos, float *__restrict__ out) {
  const int b = blockIdx.x, t = threadIdx.x;
  const int g = b >> 1;                  // group (2 blocks/group)
  const int e = g & 7;
  const int half = b & 1;
  const int n_own = (half << 9) | t;     // point index within group
  const bool isRep = (half == 0);
  const int lane = t & 63, wv = t >> 6;
  const float *pp = pos + ((size_t)e * NPTS + n_own) * 3;
  const float px = pp[0], py = pp[1], pz = pp[2];
  const float p2 = __fadd_rn(__fadd_rn(__fmul_rn(px, px), __fmul_rn(py, py)),
                             __fmul_rn(pz, pz));

  __shared__ float4 scent[NCTR];                        // persistent centroids
  __shared__ float  spx[NPTS], spy[NPTS], spz[NPTS];
  __shared__ int    slab[NPTS];
  __shared__ int    cnt[NCTR], offs[NCTR];
  __shared__ int    idx[NPTS];
  __shared__ float  redf[8];
  __shared__ double redd[4];
  __shared__ unsigned s_ctl;

  {  // stage points + initial centroids (once)
    const float *gp = pos + (size_t)e * NPTS * 3;
    for (int k = t; k < NPTS; k += NTHR) {
      spx[k] = gp[k * 3 + 0]; spy[k] = gp[k * 3 + 1]; spz[k] = gp[k * 3 + 2];
    }
    scent[t] = g_cent[(size_t)g * NCTR + t];
  }
  __syncthreads();

  int done_sT = -1;
  for (int it = 0; it < MAXIT; ++it) {
    // ---- phase A: stripe-4 argmin (bitwise same result as sequential) ----
    float best0 = __int_as_float(0x7f800000), best1 = best0,
          best2 = best0, best3 = best0;
    int im0 = 0, im1 = 0, im2 = 0, im3 = 0;
#pragma unroll 2
    for (int m = 0; m < NCTR / 4; ++m) {
      float4 c0 = scent[m], c1 = scent[m + 128], c2v = scent[m + 256],
             c3 = scent[m + 384];
      float d0 = __fadd_rn(__fsub_rn(p2, __fmul_rn(2.0f,
                    fmaf(pz, c0.z, fmaf(py, c0.y, __fmul_rn(px, c0.x))))), c0.w);
      float d1 = __fadd_rn(__fsub_rn(p2, __fmul_rn(2.0f,
                    fmaf(pz, c1.z, fmaf(py, c1.y, __fmul_rn(px, c1.x))))), c1.w);
      float d2 = __fadd_rn(__fsub_rn(p2, __fmul_rn(2.0f,
                    fmaf(pz, c2v.z, fmaf(py, c2v.y, __fmul_rn(px, c2v.x))))), c2v.w);
      float d3 = __fadd_rn(__fsub_rn(p2, __fmul_rn(2.0f,
                    fmaf(pz, c3.z, fmaf(py, c3.y, __fmul_rn(px, c3.x))))), c3.w);
      if (d0 < best0) { best0 = d0; im0 = m; }
      if (d1 < best1) { best1 = d1; im1 = m; }
      if (d2 < best2) { best2 = d2; im2 = m; }
      if (d3 < best3) { best3 = d3; im3 = m; }
    }
    float best = best0; int bm = im0;                 // stripe priority = m order
    if (best1 < best) { best = best1; bm = 128 + im1; }
    if (best2 < best) { best = best2; bm = 256 + im2; }
    if (best3 < best) { best = best3; bm = 384 + im3; }
    g_rcls[it & (RING - 1)][(size_t)g * NPTS + n_own] = bm;
    lbar2(g);

    // ---- uniform group exit decision (published at control of it-1) ----
    if (t == 0)
      s_ctl = __hip_atomic_load(&g_gdec[g * 32], __ATOMIC_RELAXED, __HIP_MEMORY_SCOPE_AGENT);
    __syncthreads();
    if (it > 0) {
      const unsigned ver = s_ctl >> 16, tv = s_ctl & 0xFFFFu;
      if (ver == (unsigned)it && tv != 0u && (int)tv - 1 <= it - 1) {
        done_sT = (int)tv - 1;                        // emit state(T) from ring
        break;                                        // uniform in BOTH blocks
      }
    }

    // ---- phase B (replicated in both blocks; identical f32 ops) ----
    slab[t]        = g_rcls[it & (RING - 1)][(size_t)g * NPTS + t];
    slab[t + NTHR] = g_rcls[it & (RING - 1)][(size_t)g * NPTS + t + NTHR];
    cnt[t] = 0;
    __syncthreads();
    atomicAdd(&cnt[slab[t]], 1);
    atomicAdd(&cnt[slab[t + NTHR]], 1);
    __syncthreads();
    int *src = cnt, *dst = offs;            // Hillis-Steele scan over 512
    for (int d = 1; d < NCTR; d <<= 1) {
      int vv = src[t];
      if (t >= d) vv += src[t - d];
      dst[t] = vv;
      __syncthreads();
      int *tmp = src; src = dst; dst = tmp;
    }
    int *incl = src, *wctr = dst;
    wctr[t] = 0;
    __syncthreads();
    {
      int c0 = slab[t];        int sl0 = atomicAdd(&wctr[c0], 1);
      idx[(c0 ? incl[c0 - 1] : 0) + sl0] = t;
      int n2 = t + NTHR; int c1 = slab[n2]; int sl1 = atomicAdd(&wctr[c1], 1);
      idx[(c1 ? incl[c1 - 1] : 0) + sl1] = n2;
    }
    __syncthreads();
    float mx = 0.0f; float4 newc4;
    {
      const int c = t;                                // one centroid per thread
      const int base = c ? incl[c - 1] : 0;
      const int kk = incl[c] - base;
      for (int i = base + 1; i < base + kk; ++i) {    // ascending point order
        int v = idx[i], j = i - 1;
        while (j >= base && idx[j] > v) { idx[j + 1] = idx[j]; --j; }
        idx[j + 1] = v;
      }
      float4 oldc = scent[c];
      float nx, ny, nz;
      if (kk > 0) {
        float sxx = 0.f, syy = 0.f, szz = 0.f;
        for (int i = 0; i < kk; ++i) {                // same adds, same order
          int n2 = idx[base + i];
          sxx = __fadd_rn(sxx, spx[n2]);
          syy = __fadd_rn(syy, spy[n2]);
          szz = __fadd_rn(szz, spz[n2]);
        }
        float fc = (float)kk;
        nx = __fdiv_rn(sxx, fc); ny = __fdiv_rn(syy, fc); nz = __fdiv_rn(szz, fc);
      } else { nx = oldc.x; ny = oldc.y; nz = oldc.z; }
      float dx = __fsub_rn(oldc.x, nx), dy = __fsub_rn(oldc.y, ny),
            dz = __fsub_rn(oldc.z, nz);
      float nr = __fsqrt_rn(__fadd_rn(__fadd_rn(__fmul_rn(dx, dx), __fmul_rn(dy, dy)),
                                      __fmul_rn(dz, dz)));
      mx = nr;
      float c2v2 = __fadd_rn(__fadd_rn(__fmul_rn(nx, nx), __fmul_rn(ny, ny)),
                             __fmul_rn(nz, nz));
      newc4 = make_float4(nx, ny, nz, c2v2);
      scent[c] = newc4;                               // LDS-persistent update
    }
    for (int off = 32; off; off >>= 1) {
      float o = __shfl_down(mx, off, 64);
      if (o > mx) mx = o;
    }
    if (lane == 0) redf[wv] = mx;
    if (isRep) g_rcent[it & (RING - 1)][(size_t)g * NCTR + t] = newc4;  // snapshot
    __syncthreads();

    // ---- control: fire-and-forget report, T resolution, decision publish ----
    if (t == 0) {
      unsigned Tl = __hip_atomic_load(&g_T[0], __ATOMIC_ACQUIRE, __HIP_MEMORY_SCOPE_AGENT);
      if (isRep) {
        if (Tl == 0u) {
          float bmx = fmaxf(fmaxf(fmaxf(redf[0], redf[1]), fmaxf(redf[2], redf[3])),
                            fmaxf(fmaxf(redf[4], redf[5]), fmaxf(redf[6], redf[7])));
          unsigned conv = (bmx < 1e-3f) ? 1u : 0u;     // f32 compare (unchanged)
          unsigned old = atomicAdd(&g_itcnt[it * 32], 0x10000u + conv);
          if ((old >> 16) == (unsigned)(NGRP - 1)) {   // closer of iteration it
            unsigned flag = 1u |
                ((((old & 0xFFFFu) + conv) == (unsigned)NGRP) ? 2u : 0u);
            __hip_atomic_store(&g_closed[it * 32], flag,
                               __ATOMIC_RELEASE, __HIP_MEMORY_SCOPE_AGENT);
            for (;;) {  // in-order watermark sweep: first all-conv t sets g_T
              unsigned w = __hip_atomic_load(&g_water[0], __ATOMIC_ACQUIRE,
                                             __HIP_MEMORY_SCOPE_AGENT);
              if (w >= (unsigned)MAXIT) break;
              unsigned f = __hip_atomic_load(&g_closed[w * 32], __ATOMIC_ACQUIRE,
                                             __HIP_MEMORY_SCOPE_AGENT);
              if (!(f & 1u)) break;
              if (f & 2u) atomicCAS(&g_T[0], 0u, w + 1u);  // before water bump
              atomicCAS(&g_water[0], w, w + 1u);
            }
          }
          Tl = __hip_atomic_load(&g_T[0], __ATOMIC_ACQUIRE, __HIP_MEMORY_SCOPE_AGENT);
        }
        __hip_atomic_store(&g_gdec[g * 32], ((unsigned)(it + 1) << 16) | Tl,
                           __ATOMIC_RELAXED, __HIP_MEMORY_SCOPE_AGENT);
        if (Tl == 0u && it + 1 >= LEAD) {              // ring overwrite guard
          long long guard = 0;
          while ((it + 1) - (int)__hip_atomic_load(&g_water[0], __ATOMIC_RELAXED,
                     __HIP_MEMORY_SCOPE_AGENT) >= LEAD) {
            if (__hip_atomic_load(&g_T[0], __ATOMIC_RELAXED, __HIP_MEMORY_SCOPE_AGENT))
              break;
            __builtin_amdgcn_s_sleep(4);
            if (++guard > (1ll << 24)) break;          // safety valve
          }
        }
      }
    }
    // no trailing barrier: next iteration's lbar2 gathers the block
  }

  // ---- tail: ran out of iterations without a resolved decision ----
  if (done_sT < 0) {
    if (t == 0) {
      unsigned Tl = 0; long long guard = 0;
      for (;;) {
        Tl = __hip_atomic_load(&g_T[0], __ATOMIC_ACQUIRE, __HIP_MEMORY_SCOPE_AGENT);
        if (Tl) break;
        if (__hip_atomic_load(&g_water[0], __ATOMIC_ACQUIRE,
                              __HIP_MEMORY_SCOPE_AGENT) >= (unsigned)MAXIT) {
          Tl = __hip_atomic_load(&g_T[0], __ATOMIC_ACQUIRE, __HIP_MEMORY_SCOPE_AGENT);
          break;
        }
        __builtin_amdgcn_s_sleep(4);
        if (++guard > (1ll << 24)) break;              // safety valve
      }
      s_ctl = Tl;
    }
    __syncthreads();
    done_sT = s_ctl ? (int)s_ctl - 1 : (MAXIT - 1);
  }

  // ---- outputs, all from ring slot sT (self/fenced writes) ----
  const int sT = done_sT;
  const int slot = sT & (RING - 1);
  out[(size_t)g * NPTS + n_own] =
      (float)g_rcls[slot][(size_t)g * NPTS + n_own];   // classification
  if (isRep) {
    float4 cc = g_rcent[slot][(size_t)g * NCTR + t];   // centroids at T
    float *o = out + OUT_CENT + ((size_t)g * NCTR + t) * 3;
    o[0] = cc.x; o[1] = cc.y; o[2] = cc.z;
    if (t < 256) {                                     // score: EXACT old f64 tree
      double s = 0.0;
      for (int k = 0; k < 4; ++k) {
        int nn = k * 256 + t;
        int c = g_rcls[slot][(size_t)g * NPTS + nn];
        float4 c4 = g_rcent[slot][(size_t)g * NCTR + c];
        s += (double)fabsf(__fsub_rn(spx[nn], c4.x)) +
             (double)fabsf(__fsub_rn(spy[nn], c4.y)) +
             (double)fabsf(__fsub_rn(spz[nn], c4.z));
      }
      for (int off = 32; off; off >>= 1) s += __shfl_down(s, off, 64);
      if (lane == 0) redd[wv] = s;
    }
    __syncthreads();
    if (t == 0) out[OUT_SCORE + g] = (float)(redd[0] + redd[1] + redd[2] + redd[3]);
  }
}

extern "C" void kernel_launch(void *const *d_in, const int *in_sizes, int n_in,
                              void *d_out, int out_size, void *d_ws, size_t ws_size,
                              hipStream_t stream) {
  const float *pos = (const float *)d_in[0];
  float *out = (float *)d_out;
  (void)d_ws; (void)ws_size; (void)in_sizes; (void)n_in; (void)out_size;

  fps_kernel<<<NGRP, 64, 0, stream>>>(pos);
  kmeans_kernel<<<NBLK, NTHR, 0, stream>>>(pos, out);
}